// Round 9
// baseline (1023.510 us; speedup 1.0000x reference)
//
#include <hip/hip_runtime.h>
#include <cstdint>
#include <cstddef>

#define N_NEU 2048
#define B_SZ  256
#define D_IN  1024
#define T_STEPS 64

typedef _Float16 f16x8 __attribute__((ext_vector_type(8)));
typedef _Float16 f16x4 __attribute__((ext_vector_type(4)));
typedef float    f32x4 __attribute__((ext_vector_type(4)));
typedef unsigned u32x4 __attribute__((ext_vector_type(4)));

#define MFMA16(a, b, c) __builtin_amdgcn_mfma_f32_16x16x32_f16((a), (b), (c), 0, 0, 0)

// ---------------- ws layout (bytes) ----------------
// Wh     [2048][2048] f16   @ 0       (8 MB)
// Wl     [2048][2048] f16   @ 8 MB    (8 MB)
// Iext   [256][2048]  f32   @ 16 MB   (2 MB)
// bitmap u16[2][256][128]   @ 18 MB   (128 KB)  spike bits: [buf][b][n/16], bit n%16
// flags  u32[512]           @ 18 MB + 128 KB    per-block epoch flags (bg*128 + ns)

// 8 bits -> 8 f16 (0.0 / 1.0)
__device__ inline f16x8 expand8(unsigned b) {
  u32x4 t;
  t[0] = ((b & 1u)   ? 0x3C00u : 0u) | ((b & 2u)   ? 0x3C000000u : 0u);
  t[1] = ((b & 4u)   ? 0x3C00u : 0u) | ((b & 8u)   ? 0x3C000000u : 0u);
  t[2] = ((b & 16u)  ? 0x3C00u : 0u) | ((b & 32u)  ? 0x3C000000u : 0u);
  t[3] = ((b & 64u)  ? 0x3C00u : 0u) | ((b & 128u) ? 0x3C000000u : 0u);
  return __builtin_bit_cast(f16x8, t);
}

// Split W_eff = adj*mask into f16 hi + f16 lo' (w ~= hi + lo'/4096). float4-vectorized. Proven r8.
__global__ __launch_bounds__(256) void k_wsplit(const float* __restrict__ adj,
                                                const float* __restrict__ mask,
                                                _Float16* __restrict__ Wh,
                                                _Float16* __restrict__ Wl,
                                                unsigned* __restrict__ flags) {
  const int idx = blockIdx.x * 256 + threadIdx.x;
  if (idx < 512) flags[idx] = 0u;
  const int total4 = (N_NEU * N_NEU) / 4;
  for (int i = idx; i < total4; i += gridDim.x * 256) {
    float4 a = ((const float4*)adj)[i];
    float4 m = ((const float4*)mask)[i];
    float w0 = a.x * m.x, w1 = a.y * m.y, w2 = a.z * m.z, w3 = a.w * m.w;
    f16x4 h, lo;
    h[0] = (_Float16)w0; lo[0] = (_Float16)((w0 - (float)h[0]) * 4096.0f);
    h[1] = (_Float16)w1; lo[1] = (_Float16)((w1 - (float)h[1]) * 4096.0f);
    h[2] = (_Float16)w2; lo[2] = (_Float16)((w2 - (float)h[2]) * 4096.0f);
    h[3] = (_Float16)w3; lo[3] = (_Float16)((w3 - (float)h[3]) * 4096.0f);
    ((f16x4*)Wh)[i] = h;
    ((f16x4*)Wl)[i] = lo;
  }
}

// I_ext = ext @ W_in^T + b_in, plain fp32. Proven absmax 0.0 (r1/r5/r6/r7).
__global__ __launch_bounds__(256) void k_iext(const float* __restrict__ ext,
                                              const float* __restrict__ Win,
                                              const float* __restrict__ bin,
                                              float* __restrict__ Iext) {
  __shared__ float At[32][68];
  __shared__ float Bt[32][68];
  const int tid = threadIdx.x;
  const int b0 = (blockIdx.x & 3) * 64;
  const int n0 = (blockIdx.x >> 2) * 64;
  const int tx = tid & 15, ty = tid >> 4;
  float acc[4][4] = {};
  for (int kt = 0; kt < D_IN / 32; ++kt) {
    const int k0 = kt * 32;
#pragma unroll
    for (int i = 0; i < 8; ++i) {
      int e = tid + i * 256;
      int kk = e & 31, row = e >> 5;
      At[kk][row] = ext[(size_t)(b0 + row) * D_IN + k0 + kk];
      Bt[kk][row] = Win[(size_t)(n0 + row) * D_IN + k0 + kk];
    }
    __syncthreads();
    for (int kk = 0; kk < 32; ++kk) {
      f32x4 a = *(const f32x4*)&At[kk][ty * 4];
      f32x4 b = *(const f32x4*)&Bt[kk][tx * 4];
#pragma unroll
      for (int i = 0; i < 4; ++i)
#pragma unroll
        for (int j = 0; j < 4; ++j) acc[i][j] += a[i] * b[j];
    }
    __syncthreads();
  }
#pragma unroll
  for (int i = 0; i < 4; ++i)
#pragma unroll
    for (int j = 0; j < 4; ++j)
      Iext[(size_t)(b0 + ty * 4 + i) * N_NEU + n0 + tx * 4 + j] = acc[i][j] + bin[n0 + tx * 4 + j];
}

// Split-K tree reduction over 8 waves via LDS, 16-col variant (same tree/order as r5-r7).
// red: float[4][16][64] (p, col, row^((col&7)<<2)); 16 KB.
__device__ inline void reduce_tree16(float (&outv)[2], const f32x4 (&c)[4],
                                     float* red, int tid) {
  const int lane = tid & 63, wv = tid >> 6;
  const int cb = lane & 15, rq = (lane >> 4) << 2;
  if (wv >= 4) {
    const int p = wv - 4;
#pragma unroll
    for (int mt = 0; mt < 4; ++mt) {
      const int r0 = (mt * 16 + rq) ^ ((cb & 7) << 2);
      *(f32x4*)(red + (p * 16 + cb) * 64 + r0) = c[mt];
    }
  }
  __syncthreads();
  if (wv < 4) {
#pragma unroll
    for (int mt = 0; mt < 4; ++mt) {
      const int r0 = (mt * 16 + rq) ^ ((cb & 7) << 2);
      float* p2 = red + (wv * 16 + cb) * 64 + r0;
      f32x4 o = *(const f32x4*)p2;
      o += c[mt];
      *(f32x4*)p2 = o;
    }
  }
  __syncthreads();
#pragma unroll
  for (int j = 0; j < 2; ++j) {
    const int o = j * 512 + tid;
    const int row = o >> 4, col = o & 15;
    const int rs = row ^ ((col & 7) << 2);
    float s = 0.0f;
#pragma unroll
    for (int p = 0; p < 4; ++p) s += red[(p * 16 + col) * 64 + rs];
    outv[j] = s;
  }
}

// Persistent fused LIF kernel. 512 blocks x 512 thr, 2 blocks/CU (co-resident pair = different
// bg groups -> independent barriers overlap: one block computes while the other waits).
// Block (bg 0..3, ns 0..127): rows bg*64..+64, cols ns*16..+16. 8 waves split K (256 each).
// Wh+Wl resident in VGPRs (96 regs); __launch_bounds__(512,4) caps at 128 -> residency guaranteed.
__global__ __launch_bounds__(512, 4) void k_fused6(
    const _Float16* __restrict__ Wh, const _Float16* __restrict__ Wl,
    const float* __restrict__ Iext, unsigned short* __restrict__ bitmap,
    unsigned* __restrict__ flags, float* __restrict__ out) {
  __shared__ float red[4 * 16 * 64];               // 16 KB
  __shared__ unsigned long long bm_lds[64 * 32];   // 16 KB

  const int tid = threadIdx.x;
  const int lane = tid & 63;
  const int kw = tid >> 6;       // wave id = split-K index 0..7
  const int l15 = lane & 15;
  const int klo = lane >> 4;     // 0..3
  const int sh = klo * 8;
  const int bid = blockIdx.x;
  const int bg = bid >> 7;          // 0..3 batch group (64 rows)
  const int ns = bid & 127;         // 0..127 neuron slice (16 cols)
  const int n0 = ns * 16;
  const float inv4096 = 1.0f / 4096.0f;
  const f32x4 z4 = {0.f, 0.f, 0.f, 0.f};

  // ---------- per-thread Iext (proven fp32 values from k_iext) ----------
  float Iext_r[2];
#pragma unroll
  for (int j = 0; j < 2; ++j)
    Iext_r[j] = Iext[(size_t)(bg * 64 + j * 32 + (tid >> 4)) * N_NEU + n0 + (tid & 15)];

  // ---------- resident Wh AND Wl fragments (pure-register K-loop) ----------
  const _Float16* whb = Wh + (size_t)(n0 + l15) * N_NEU + kw * 256 + klo * 8;
  const _Float16* wlb = Wl + (size_t)(n0 + l15) * N_NEU + kw * 256 + klo * 8;
  f16x8 whf[8], wlf[8];
#pragma unroll
  for (int kcl = 0; kcl < 8; ++kcl) {
    whf[kcl] = *(const f16x8*)(whb + kcl * 32);
    wlf[kcl] = *(const f16x8*)(wlb + kcl * 32);
  }

  float V[2] = {0.f, 0.f};
  unsigned cnt[2] = {0u, 0u};

  for (int t = 0; t < T_STEPS; ++t) {
    float cI[2];
    if (t == 0) {
      cI[0] = cI[1] = 0.0f;
    } else {
      // ---- stage spike bitmap slab (16 KB) into LDS: coalesced LLC-atomic u64 loads ----
      const unsigned long long* src =
          (const unsigned long long*)bitmap + (size_t)(t & 1) * 8192 + (size_t)(bg * 64) * 32;
#pragma unroll
      for (int i = 0; i < 4; ++i) {
        const int g = i * 512 + tid;         // u64 index 0..2047
        const int row = g >> 5, pr = g & 31;
        unsigned long long v =
            __hip_atomic_load(src + g, __ATOMIC_RELAXED, __HIP_MEMORY_SCOPE_AGENT);
        bm_lds[row * 32 + (pr ^ (row & 31))] = v;
      }
      __syncthreads();

      // ---- K-loop: pure-register MFMA ----
      f32x4 acch[4], accl[4];
#pragma unroll
      for (int mt = 0; mt < 4; ++mt) { acch[mt] = z4; accl[mt] = z4; }

#pragma unroll
      for (int mt = 0; mt < 4; ++mt) {
        const int row = mt * 16 + l15;
        const int x = row & 31;
        unsigned long long q[4];
#pragma unroll
        for (int i = 0; i < 4; ++i) q[i] = bm_lds[row * 32 + ((kw * 4 + i) ^ x)];
#pragma unroll
        for (int kcl = 0; kcl < 8; ++kcl) {
          const unsigned word = (unsigned)(q[kcl >> 1] >> (32 * (kcl & 1)));
          const f16x8 a = expand8((word >> sh) & 0xFFu);
          acch[mt] = MFMA16(a, whf[kcl], acch[mt]);
          accl[mt] = MFMA16(a, wlf[kcl], accl[mt]);
        }
      }
      f32x4 cb[4];
#pragma unroll
      for (int mt = 0; mt < 4; ++mt) cb[mt] = acch[mt] + accl[mt] * inv4096;
      reduce_tree16(cI, cb, red, tid);
    }

    // ---------- fused LIF epilogue; u16 spike stores -> bitmap[(t+1)&1] ----------
    const size_t wb = (size_t)((t + 1) & 1) * 32768;
#pragma unroll
    for (int j = 0; j < 2; ++j) {
      float I = cI[j] + Iext_r[j];
      float v = 0.9f * V[j] + I;
      bool sp = (v - 1.0f) >= 0.0f;
      V[j] = sp ? 0.0f : v;
      cnt[j] += sp ? 1u : 0u;
      if (t < T_STEPS - 1) {
        unsigned long long ba = __ballot(sp);
        // lane-group s = lane>>4 holds row bg*64 + j*32 + kw*4 + s, cols 0..15 in bits s*16..+15
        if ((lane & 15) == 0) {
          const int s = lane >> 4;
          const int rowfull = bg * 64 + j * 32 + kw * 4 + s;
          __hip_atomic_store(bitmap + wb + (size_t)rowfull * 128 + ns,
                             (unsigned short)((ba >> (s * 16)) & 0xFFFFull),
                             __ATOMIC_RELAXED, __HIP_MEMORY_SCOPE_AGENT);
        }
      }
    }

    // ---------- group barrier: per-block epoch flags (r7-proven topology) ----------
    if (t < T_STEPS - 1) {
      asm volatile("s_waitcnt vmcnt(0)" ::: "memory");  // spike stores acked at LLC
      __syncthreads();
      if (tid == 0)
        __hip_atomic_store(&flags[bg * 128 + ns], (unsigned)(t + 1),
                           __ATOMIC_RELAXED, __HIP_MEMORY_SCOPE_AGENT);
      if (kw == 0) {
        const unsigned tgt = (unsigned)(t + 1);
        while (true) {
          unsigned v0 = __hip_atomic_load(&flags[bg * 128 + lane],
                                          __ATOMIC_RELAXED, __HIP_MEMORY_SCOPE_AGENT);
          unsigned v1 = __hip_atomic_load(&flags[bg * 128 + 64 + lane],
                                          __ATOMIC_RELAXED, __HIP_MEMORY_SCOPE_AGENT);
          if (__all(v0 >= tgt && v1 >= tgt)) break;
          __builtin_amdgcn_s_sleep(1);
        }
      }
      __syncthreads();
    }
  }

  // ---------- write firing rates ----------
#pragma unroll
  for (int j = 0; j < 2; ++j) {
    const int row = j * 32 + (tid >> 4);
    out[(size_t)(bg * 64 + row) * N_NEU + n0 + (tid & 15)] = (float)cnt[j] * 0.015625f;
  }
}

extern "C" void kernel_launch(void* const* d_in, const int* in_sizes, int n_in,
                              void* d_out, int out_size, void* d_ws, size_t ws_size,
                              hipStream_t stream) {
  (void)in_sizes; (void)n_in; (void)out_size; (void)ws_size;
  const float* ext  = (const float*)d_in[0];
  const float* Win  = (const float*)d_in[1];
  const float* bin  = (const float*)d_in[2];
  const float* adj  = (const float*)d_in[3];
  const float* mask = (const float*)d_in[4];
  unsigned char* ws = (unsigned char*)d_ws;

  _Float16* Wh   = (_Float16*)(ws);
  _Float16* Wl   = (_Float16*)(ws + (size_t)(8u << 20));
  float*    Iext = (float*)   (ws + (size_t)(16u << 20));
  unsigned short* bitmap = (unsigned short*)(ws + (size_t)(18u << 20));
  unsigned* flags = (unsigned*)(ws + (size_t)(18u << 20) + 131072u);
  float* out = (float*)d_out;

  hipLaunchKernelGGL(k_wsplit, dim3(2048), dim3(256), 0, stream, adj, mask, Wh, Wl, flags);
  hipLaunchKernelGGL(k_iext,   dim3(128),  dim3(256), 0, stream, ext, Win, bin, Iext);
  hipLaunchKernelGGL(k_fused6, dim3(512),  dim3(512), 0, stream,
                     Wh, Wl, Iext, bitmap, flags, out);
}

// Round 10
// 625.659 us; speedup vs baseline: 1.6359x; 1.6359x over previous
//
#include <hip/hip_runtime.h>
#include <cstdint>
#include <cstddef>

#define N_NEU 2048
#define D_IN  1024
#define T_STEPS 64

typedef _Float16 f16x8 __attribute__((ext_vector_type(8)));
typedef _Float16 f16x4 __attribute__((ext_vector_type(4)));
typedef float    f32x4 __attribute__((ext_vector_type(4)));
typedef unsigned u32x4 __attribute__((ext_vector_type(4)));

#define MFMA16(a, b, c) __builtin_amdgcn_mfma_f32_16x16x32_f16((a), (b), (c), 0, 0, 0)

// ---------------- ws layout (bytes) ----------------
// Wh     [2048][2048] f16   @ 0       (8 MB)
// Wl     [2048][2048] f16   @ 8 MB    (8 MB)
// Iext   [256][2048]  f32   @ 16 MB   (2 MB)
// bitmap u32[2][256][64]    @ 18 MB   (128 KB)   spike bits: [buf][b][n/32], bit n%32
// flags  u32[512]           @ 18 MB + 128 KB     per-(group,ns) epoch flags: [g*64 + ns]

// 8 bits -> 8 f16 (0.0 / 1.0)
__device__ inline f16x8 expand8(unsigned b) {
  u32x4 t;
  t[0] = ((b & 1u)   ? 0x3C00u : 0u) | ((b & 2u)   ? 0x3C000000u : 0u);
  t[1] = ((b & 4u)   ? 0x3C00u : 0u) | ((b & 8u)   ? 0x3C000000u : 0u);
  t[2] = ((b & 16u)  ? 0x3C00u : 0u) | ((b & 32u)  ? 0x3C000000u : 0u);
  t[3] = ((b & 64u)  ? 0x3C00u : 0u) | ((b & 128u) ? 0x3C000000u : 0u);
  return __builtin_bit_cast(f16x8, t);
}

// Split W_eff = adj*mask into f16 hi + f16 lo' (w ~= hi + lo'/4096). Proven r8/r9.
__global__ __launch_bounds__(256) void k_wsplit(const float* __restrict__ adj,
                                                const float* __restrict__ mask,
                                                _Float16* __restrict__ Wh,
                                                _Float16* __restrict__ Wl,
                                                unsigned* __restrict__ flags) {
  const int idx = blockIdx.x * 256 + threadIdx.x;
  if (idx < 512) flags[idx] = 0u;
  const int total4 = (N_NEU * N_NEU) / 4;
  for (int i = idx; i < total4; i += gridDim.x * 256) {
    float4 a = ((const float4*)adj)[i];
    float4 m = ((const float4*)mask)[i];
    float w0 = a.x * m.x, w1 = a.y * m.y, w2 = a.z * m.z, w3 = a.w * m.w;
    f16x4 h, lo;
    h[0] = (_Float16)w0; lo[0] = (_Float16)((w0 - (float)h[0]) * 4096.0f);
    h[1] = (_Float16)w1; lo[1] = (_Float16)((w1 - (float)h[1]) * 4096.0f);
    h[2] = (_Float16)w2; lo[2] = (_Float16)((w2 - (float)h[2]) * 4096.0f);
    h[3] = (_Float16)w3; lo[3] = (_Float16)((w3 - (float)h[3]) * 4096.0f);
    ((f16x4*)Wh)[i] = h;
    ((f16x4*)Wl)[i] = lo;
  }
}

// I_ext = ext @ W_in^T + b_in, plain fp32. Proven absmax 0.0 (r1/r5-r9).
__global__ __launch_bounds__(256) void k_iext(const float* __restrict__ ext,
                                              const float* __restrict__ Win,
                                              const float* __restrict__ bin,
                                              float* __restrict__ Iext) {
  __shared__ float At[32][68];
  __shared__ float Bt[32][68];
  const int tid = threadIdx.x;
  const int b0 = (blockIdx.x & 3) * 64;
  const int n0 = (blockIdx.x >> 2) * 64;
  const int tx = tid & 15, ty = tid >> 4;
  float acc[4][4] = {};
  for (int kt = 0; kt < D_IN / 32; ++kt) {
    const int k0 = kt * 32;
#pragma unroll
    for (int i = 0; i < 8; ++i) {
      int e = tid + i * 256;
      int kk = e & 31, row = e >> 5;
      At[kk][row] = ext[(size_t)(b0 + row) * D_IN + k0 + kk];
      Bt[kk][row] = Win[(size_t)(n0 + row) * D_IN + k0 + kk];
    }
    __syncthreads();
    for (int kk = 0; kk < 32; ++kk) {
      f32x4 a = *(const f32x4*)&At[kk][ty * 4];
      f32x4 b = *(const f32x4*)&Bt[kk][tx * 4];
#pragma unroll
      for (int i = 0; i < 4; ++i)
#pragma unroll
        for (int j = 0; j < 4; ++j) acc[i][j] += a[i] * b[j];
    }
    __syncthreads();
  }
#pragma unroll
  for (int i = 0; i < 4; ++i)
#pragma unroll
    for (int j = 0; j < 4; ++j)
      Iext[(size_t)(b0 + ty * 4 + i) * N_NEU + n0 + tx * 4 + j] = acc[i][j] + bin[n0 + tx * 4 + j];
}

// Persistent fused LIF kernel, dual-group software pipeline.
// 256 blocks x 512 thr (1/CU). Block (gp 0..3, ns 0..63) handles groups gA=gp, gB=gp+4
// (32 batch rows each) x cols ns*32..+32. 8 waves split K (256 each); Wh+Wl resident in
// VGPRs (shared by both groups). While group X computes (~2us), group Y's barrier flags
// settle and Y's bitmap loads are already in flight -> LLC latency hidden.
__global__ __launch_bounds__(512, 2) void k_fused7(
    const _Float16* __restrict__ Wh, const _Float16* __restrict__ Wl,
    const float* __restrict__ Iext, unsigned* __restrict__ bitmap,
    unsigned* __restrict__ flags, float* __restrict__ out) {
  __shared__ float red[4 * 32 * 32];            // 16 KB (split-K reduce)
  __shared__ unsigned long long bmA[32 * 32];   // 8 KB
  __shared__ unsigned long long bmB[32 * 32];   // 8 KB

  const int tid = threadIdx.x;
  const int lane = tid & 63;
  const int kw = tid >> 6;        // wave id = split-K index 0..7
  const int l15 = lane & 15;
  const int klo = lane >> 4;      // 0..3
  const int sh = klo * 8;
  const int gp = blockIdx.x >> 6; // 0..3
  const int ns = blockIdx.x & 63; // 0..63
  const int n0 = ns * 32;
  const int gA = gp, gB = gp + 4; // row groups: g*32 .. g*32+32
  const float inv4096 = 1.0f / 4096.0f;
  const f32x4 z4 = {0.f, 0.f, 0.f, 0.f};
  const unsigned long long* bm64 = (const unsigned long long*)bitmap;

  // ---------- per-thread Iext ----------
  float IxA[2], IxB[2];
#pragma unroll
  for (int j = 0; j < 2; ++j) {
    IxA[j] = Iext[(size_t)(gA * 32 + j * 16 + (tid >> 5)) * N_NEU + n0 + (tid & 31)];
    IxB[j] = Iext[(size_t)(gB * 32 + j * 16 + (tid >> 5)) * N_NEU + n0 + (tid & 31)];
  }

  // ---------- resident Wh + Wl fragments (shared by both groups) ----------
  const _Float16* whb = Wh + (size_t)(n0 + l15) * N_NEU + kw * 256 + klo * 8;
  const _Float16* wlb = Wl + (size_t)(n0 + l15) * N_NEU + kw * 256 + klo * 8;
  f16x8 whf[2][8], wlf[2][8];
#pragma unroll
  for (int nt = 0; nt < 2; ++nt)
#pragma unroll
    for (int kcl = 0; kcl < 8; ++kcl) {
      whf[nt][kcl] = *(const f16x8*)(whb + nt * 16 * N_NEU + kcl * 32);
      wlf[nt][kcl] = *(const f16x8*)(wlb + nt * 16 * N_NEU + kcl * 32);
    }

  float VA[2] = {0.f, 0.f}, VB[2] = {0.f, 0.f};
  unsigned cA[2] = {0u, 0u}, cB[2] = {0u, 0u};
  unsigned long long vA[2], vB[2];

  // poll: all 64 lanes load 64 flags of group g; exit when all >= tgt
  auto poll = [&](int g, unsigned tgt) {
    while (true) {
      unsigned v = __hip_atomic_load(&flags[g * 64 + lane],
                                     __ATOMIC_RELAXED, __HIP_MEMORY_SCOPE_AGENT);
      if (__all(v >= tgt)) break;
      __builtin_amdgcn_s_sleep(1);
    }
  };
  // issue 2 coalesced u64 LLC loads of group g's spike slab (buf)
  auto issue = [&](int g, int buf, unsigned long long (&v)[2]) {
    const unsigned long long* src = bm64 + (size_t)buf * 8192 + (size_t)g * 1024;
#pragma unroll
    for (int i = 0; i < 2; ++i)
      v[i] = __hip_atomic_load(src + i * 512 + tid, __ATOMIC_RELAXED, __HIP_MEMORY_SCOPE_AGENT);
  };
  // write staged words into swizzled LDS
  auto stage = [&](unsigned long long* bm, const unsigned long long (&v)[2]) {
#pragma unroll
    for (int i = 0; i < 2; ++i) {
      const int e = i * 512 + tid, row = e >> 5, pr = e & 31;
      bm[row * 32 + (pr ^ row)] = v[i];
    }
  };
  // K-loop + split-K reduce -> cI[2] (summation order identical to r7)
  auto gemm = [&](const unsigned long long* bm, float (&cI)[2]) {
    f32x4 acch[2][2], accl[2][2];
#pragma unroll
    for (int mt = 0; mt < 2; ++mt)
#pragma unroll
      for (int nt = 0; nt < 2; ++nt) { acch[mt][nt] = z4; accl[mt][nt] = z4; }
#pragma unroll
    for (int mt = 0; mt < 2; ++mt) {
      const int row = mt * 16 + l15;
      unsigned long long q[4];
#pragma unroll
      for (int i = 0; i < 4; ++i) q[i] = bm[row * 32 + ((kw * 4 + i) ^ row)];
#pragma unroll
      for (int kcl = 0; kcl < 8; ++kcl) {
        const unsigned word = (unsigned)(q[kcl >> 1] >> (32 * (kcl & 1)));
        const f16x8 a = expand8((word >> sh) & 0xFFu);
        acch[mt][0] = MFMA16(a, whf[0][kcl], acch[mt][0]);
        accl[mt][0] = MFMA16(a, wlf[0][kcl], accl[mt][0]);
        acch[mt][1] = MFMA16(a, whf[1][kcl], acch[mt][1]);
        accl[mt][1] = MFMA16(a, wlf[1][kcl], accl[mt][1]);
      }
    }
    f32x4 cb[2][2];
#pragma unroll
    for (int mt = 0; mt < 2; ++mt)
#pragma unroll
      for (int nt = 0; nt < 2; ++nt) cb[mt][nt] = acch[mt][nt] + accl[mt][nt] * inv4096;
    // tree: waves 4-7 store, 0-3 add, then per-thread sum of 4 partials
    const int cbn = lane & 15, rq = (lane >> 4) << 2;
    if (kw >= 4) {
      const int p = kw - 4;
#pragma unroll
      for (int mt = 0; mt < 2; ++mt)
#pragma unroll
        for (int nt = 0; nt < 2; ++nt) {
          const int col = nt * 16 + cbn;
          const int r0 = (mt * 16 + rq) ^ ((col & 7) << 2);
          *(f32x4*)(red + (p * 32 + col) * 32 + r0) = cb[mt][nt];
        }
    }
    __syncthreads();
    if (kw < 4) {
#pragma unroll
      for (int mt = 0; mt < 2; ++mt)
#pragma unroll
        for (int nt = 0; nt < 2; ++nt) {
          const int col = nt * 16 + cbn;
          const int r0 = (mt * 16 + rq) ^ ((col & 7) << 2);
          float* p2 = red + (kw * 32 + col) * 32 + r0;
          f32x4 o = *(const f32x4*)p2;
          o += cb[mt][nt];
          *(f32x4*)p2 = o;
        }
    }
    __syncthreads();
#pragma unroll
    for (int j = 0; j < 2; ++j) {
      const int o = j * 512 + tid;
      const int row = o >> 5, col = o & 31;
      const int rs = row ^ ((col & 7) << 2);
      float s = 0.0f;
#pragma unroll
      for (int p = 0; p < 4; ++p) s += red[(p * 32 + col) * 32 + rs];
      cI[j] = s;
    }
  };
  // LIF + spike ballot store to bitmap[nbuf]
  auto lif = [&](const float (&cI)[2], const float (&Ix)[2], float (&V)[2],
                 unsigned (&cnt)[2], int g, int nbuf, bool dostore) {
#pragma unroll
    for (int j = 0; j < 2; ++j) {
      float I = cI[j] + Ix[j];
      float v = 0.9f * V[j] + I;
      bool sp = (v - 1.0f) >= 0.0f;
      V[j] = sp ? 0.0f : v;
      cnt[j] += sp ? 1u : 0u;
      if (dostore) {
        unsigned long long ba = __ballot(sp);
        const int rowf = g * 32 + j * 16 + kw * 2;  // lanes 0-31: rowf, 32-63: rowf+1
        if (lane == 0)
          __hip_atomic_store(bitmap + (size_t)nbuf * 16384 + (size_t)rowf * 64 + ns,
                             (unsigned)ba, __ATOMIC_RELAXED, __HIP_MEMORY_SCOPE_AGENT);
        else if (lane == 32)
          __hip_atomic_store(bitmap + (size_t)nbuf * 16384 + (size_t)(rowf + 1) * 64 + ns,
                             (unsigned)(ba >> 32), __ATOMIC_RELAXED, __HIP_MEMORY_SCOPE_AGENT);
      }
    }
  };
  auto drain_flag = [&](int g, unsigned val, bool doflag) {
    asm volatile("s_waitcnt vmcnt(0)" ::: "memory");  // spike stores acked at LLC
    __syncthreads();
    if (doflag && tid == 0)
      __hip_atomic_store(&flags[g * 64 + ns], val, __ATOMIC_RELAXED, __HIP_MEMORY_SCOPE_AGENT);
  };

  // ---------- t = 0: Iext-only LIF for both groups; spikes -> buf 1; flags = 1 ----------
  {
    const float cz[2] = {0.f, 0.f};
    lif(cz, IxA, VA, cA, gA, 1, true);
    lif(cz, IxB, VB, cB, gB, 1, true);
    asm volatile("s_waitcnt vmcnt(0)" ::: "memory");
    __syncthreads();
    if (tid == 0) {
      __hip_atomic_store(&flags[gA * 64 + ns], 1u, __ATOMIC_RELAXED, __HIP_MEMORY_SCOPE_AGENT);
      __hip_atomic_store(&flags[gB * 64 + ns], 1u, __ATOMIC_RELAXED, __HIP_MEMORY_SCOPE_AGENT);
    }
    poll(gA, 1u);
    issue(gA, 1, vA);
  }

  for (int t = 1; t < T_STEPS; ++t) {
    const int cbuf = t & 1, nbuf = (t + 1) & 1;
    const bool last = (t == T_STEPS - 1);
    float cI[2];

    // ---- phase A ----
    stage(bmA, vA);
    __syncthreads();
    poll(gB, (unsigned)t);            // B(t) flagged during others' previous B phase
    issue(gB, cbuf, vB);              // in flight under A's compute
    gemm(bmA, cI);
    lif(cI, IxA, VA, cA, gA, nbuf, !last);
    drain_flag(gA, (unsigned)(t + 1), !last);

    // ---- phase B ----
    stage(bmB, vB);
    __syncthreads();
    if (!last) {
      poll(gA, (unsigned)(t + 1));    // A(t+1) flagged during others' A phase just done
      issue(gA, nbuf, vA);            // in flight under B's compute
    }
    gemm(bmB, cI);
    lif(cI, IxB, VB, cB, gB, nbuf, !last);
    drain_flag(gB, (unsigned)(t + 1), !last);
  }

  // ---------- write firing rates ----------
#pragma unroll
  for (int j = 0; j < 2; ++j) {
    const int rA = gA * 32 + j * 16 + (tid >> 5);
    const int rB = gB * 32 + j * 16 + (tid >> 5);
    out[(size_t)rA * N_NEU + n0 + (tid & 31)] = (float)cA[j] * 0.015625f;
    out[(size_t)rB * N_NEU + n0 + (tid & 31)] = (float)cB[j] * 0.015625f;
  }
}

extern "C" void kernel_launch(void* const* d_in, const int* in_sizes, int n_in,
                              void* d_out, int out_size, void* d_ws, size_t ws_size,
                              hipStream_t stream) {
  (void)in_sizes; (void)n_in; (void)out_size; (void)ws_size;
  const float* ext  = (const float*)d_in[0];
  const float* Win  = (const float*)d_in[1];
  const float* bin  = (const float*)d_in[2];
  const float* adj  = (const float*)d_in[3];
  const float* mask = (const float*)d_in[4];
  unsigned char* ws = (unsigned char*)d_ws;

  _Float16* Wh   = (_Float16*)(ws);
  _Float16* Wl   = (_Float16*)(ws + (size_t)(8u << 20));
  float*    Iext = (float*)   (ws + (size_t)(16u << 20));
  unsigned* bitmap = (unsigned*)(ws + (size_t)(18u << 20));
  unsigned* flags  = (unsigned*)(ws + (size_t)(18u << 20) + 131072u);
  float* out = (float*)d_out;

  hipLaunchKernelGGL(k_wsplit, dim3(2048), dim3(256), 0, stream, adj, mask, Wh, Wl, flags);
  hipLaunchKernelGGL(k_iext,   dim3(128),  dim3(256), 0, stream, ext, Win, bin, Iext);
  hipLaunchKernelGGL(k_fused7, dim3(256),  dim3(512), 0, stream,
                     Wh, Wl, Iext, bitmap, flags, out);
}

// Round 11
// 443.907 us; speedup vs baseline: 2.3057x; 1.4094x over previous
//
#include <hip/hip_runtime.h>
#include <cstdint>
#include <cstddef>

#define N_NEU 2048
#define D_IN  1024
#define T_STEPS 64

typedef _Float16 f16x8 __attribute__((ext_vector_type(8)));
typedef _Float16 f16x4 __attribute__((ext_vector_type(4)));
typedef float    f32x4 __attribute__((ext_vector_type(4)));
typedef unsigned u32x4 __attribute__((ext_vector_type(4)));

#define MFMA16(a, b, c) __builtin_amdgcn_mfma_f32_16x16x32_f16((a), (b), (c), 0, 0, 0)

// ---------------- ws layout (bytes) ----------------
// Wh   [2048][2048] f16   @ 0       (8 MB)
// Wl   [2048][2048] f16   @ 8 MB    (8 MB)
// Iext [256][2048]  f32   @ 16 MB   (2 MB)
// bmv  u64[2][256][64]    @ 18 MB   (256 KB)  (tag<<32)|bits: word (row, n/32), bit n%32

// 8 bits -> 8 f16 (0.0 / 1.0)
__device__ inline f16x8 expand8(unsigned b) {
  u32x4 t;
  t[0] = ((b & 1u)   ? 0x3C00u : 0u) | ((b & 2u)   ? 0x3C000000u : 0u);
  t[1] = ((b & 4u)   ? 0x3C00u : 0u) | ((b & 8u)   ? 0x3C000000u : 0u);
  t[2] = ((b & 16u)  ? 0x3C00u : 0u) | ((b & 32u)  ? 0x3C000000u : 0u);
  t[3] = ((b & 64u)  ? 0x3C00u : 0u) | ((b & 128u) ? 0x3C000000u : 0u);
  return __builtin_bit_cast(f16x8, t);
}

// Split W_eff = adj*mask into f16 hi + f16 lo' (w ~= hi + lo'/4096). Zeroes bmv (replay!).
__global__ __launch_bounds__(256) void k_wsplit(const float* __restrict__ adj,
                                                const float* __restrict__ mask,
                                                _Float16* __restrict__ Wh,
                                                _Float16* __restrict__ Wl,
                                                unsigned long long* __restrict__ bmv) {
  const int idx = blockIdx.x * 256 + threadIdx.x;
  if (idx < 2 * 256 * 64) bmv[idx] = 0ull;
  const int total4 = (N_NEU * N_NEU) / 4;
  for (int i = idx; i < total4; i += gridDim.x * 256) {
    float4 a = ((const float4*)adj)[i];
    float4 m = ((const float4*)mask)[i];
    float w0 = a.x * m.x, w1 = a.y * m.y, w2 = a.z * m.z, w3 = a.w * m.w;
    f16x4 h, lo;
    h[0] = (_Float16)w0; lo[0] = (_Float16)((w0 - (float)h[0]) * 4096.0f);
    h[1] = (_Float16)w1; lo[1] = (_Float16)((w1 - (float)h[1]) * 4096.0f);
    h[2] = (_Float16)w2; lo[2] = (_Float16)((w2 - (float)h[2]) * 4096.0f);
    h[3] = (_Float16)w3; lo[3] = (_Float16)((w3 - (float)h[3]) * 4096.0f);
    ((f16x4*)Wh)[i] = h;
    ((f16x4*)Wl)[i] = lo;
  }
}

// I_ext = ext @ W_in^T + b_in, plain fp32. Proven absmax 0.0 (r1/r5-r10).
__global__ __launch_bounds__(256) void k_iext(const float* __restrict__ ext,
                                              const float* __restrict__ Win,
                                              const float* __restrict__ bin,
                                              float* __restrict__ Iext) {
  __shared__ float At[32][68];
  __shared__ float Bt[32][68];
  const int tid = threadIdx.x;
  const int b0 = (blockIdx.x & 3) * 64;
  const int n0 = (blockIdx.x >> 2) * 64;
  const int tx = tid & 15, ty = tid >> 4;
  float acc[4][4] = {};
  for (int kt = 0; kt < D_IN / 32; ++kt) {
    const int k0 = kt * 32;
#pragma unroll
    for (int i = 0; i < 8; ++i) {
      int e = tid + i * 256;
      int kk = e & 31, row = e >> 5;
      At[kk][row] = ext[(size_t)(b0 + row) * D_IN + k0 + kk];
      Bt[kk][row] = Win[(size_t)(n0 + row) * D_IN + k0 + kk];
    }
    __syncthreads();
    for (int kk = 0; kk < 32; ++kk) {
      f32x4 a = *(const f32x4*)&At[kk][ty * 4];
      f32x4 b = *(const f32x4*)&Bt[kk][tx * 4];
#pragma unroll
      for (int i = 0; i < 4; ++i)
#pragma unroll
        for (int j = 0; j < 4; ++j) acc[i][j] += a[i] * b[j];
    }
    __syncthreads();
  }
#pragma unroll
  for (int i = 0; i < 4; ++i)
#pragma unroll
    for (int j = 0; j < 4; ++j)
      Iext[(size_t)(b0 + ty * 4 + i) * N_NEU + n0 + tx * 4 + j] = acc[i][j] + bin[n0 + tx * 4 + j];
}

// Persistent fused LIF kernel, dual-group, ZERO-BARRIER dataflow.
// 256 blocks x 512 thr (1/CU). Block (gp 0..3, ns 0..63): groups gA=gp, gB=gp+4 (32 rows
// each) x cols ns*32..+32. 8 waves split K. Wh+Wl resident in VGPRs (shared by groups).
// Spike words self-validate via epoch tags; speculative loads issued a full compute-phase
// before their tag check -> first-try hit in steady state, no polling storm, no fences.
__global__ __launch_bounds__(512, 2) void k_fused8(
    const _Float16* __restrict__ Wh, const _Float16* __restrict__ Wl,
    const float* __restrict__ Iext, unsigned long long* __restrict__ bmv,
    float* __restrict__ out) {
  __shared__ float red[4 * 32 * 32];   // 16 KB split-K reduce (layout verbatim r10)
  __shared__ unsigned bmA[32 * 64];    // 8 KB group-A spike bits
  __shared__ unsigned bmB[32 * 64];    // 8 KB group-B spike bits

  const int tid = threadIdx.x;
  const int lane = tid & 63;
  const int kw = tid >> 6;        // wave id = split-K index 0..7
  const int l15 = lane & 15;
  const int klo = lane >> 4;      // 0..3
  const int sh = klo * 8;
  const int gp = blockIdx.x >> 6; // 0..3
  const int ns = blockIdx.x & 63; // 0..63
  const int n0 = ns * 32;
  const int gA = gp, gB = gp + 4;
  const float inv4096 = 1.0f / 4096.0f;
  const f32x4 z4 = {0.f, 0.f, 0.f, 0.f};

  // ---------- per-thread Iext ----------
  float IxA[2], IxB[2];
#pragma unroll
  for (int j = 0; j < 2; ++j) {
    IxA[j] = Iext[(size_t)(gA * 32 + j * 16 + (tid >> 5)) * N_NEU + n0 + (tid & 31)];
    IxB[j] = Iext[(size_t)(gB * 32 + j * 16 + (tid >> 5)) * N_NEU + n0 + (tid & 31)];
  }

  // ---------- resident Wh + Wl fragments ----------
  const _Float16* whb = Wh + (size_t)(n0 + l15) * N_NEU + kw * 256 + klo * 8;
  const _Float16* wlb = Wl + (size_t)(n0 + l15) * N_NEU + kw * 256 + klo * 8;
  f16x8 whf[2][8], wlf[2][8];
#pragma unroll
  for (int nt = 0; nt < 2; ++nt)
#pragma unroll
    for (int kcl = 0; kcl < 8; ++kcl) {
      whf[nt][kcl] = *(const f16x8*)(whb + nt * 16 * N_NEU + kcl * 32);
      wlf[nt][kcl] = *(const f16x8*)(wlb + nt * 16 * N_NEU + kcl * 32);
    }

  float VA[2] = {0.f, 0.f}, VB[2] = {0.f, 0.f};
  unsigned cA[2] = {0u, 0u}, cB[2] = {0u, 0u};
  unsigned long long vA[4], vB[4];

  // speculative one-shot load of group g's 2048-word slab (4 coalesced u64/thread)
  auto spec_issue = [&](int g, int buf, unsigned long long (&v)[4]) {
    const unsigned long long* src = bmv + (size_t)buf * 16384 + (size_t)g * 2048 + tid;
#pragma unroll
    for (int i = 0; i < 4; ++i)
      v[i] = __hip_atomic_load(src + (size_t)i * 512, __ATOMIC_RELAXED, __HIP_MEMORY_SCOPE_AGENT);
  };
  // validate tags; retry only stale words (rare: issued a compute-phase ago)
  auto check_retry = [&](int g, int buf, unsigned want, unsigned long long (&v)[4]) {
    const unsigned long long* src = bmv + (size_t)buf * 16384 + (size_t)g * 2048 + tid;
    unsigned need = 0u;
#pragma unroll
    for (int i = 0; i < 4; ++i)
      if ((unsigned)(v[i] >> 32) != want) need |= 1u << i;
    while (need) {
      __builtin_amdgcn_s_sleep(2);
#pragma unroll
      for (int i = 0; i < 4; ++i)
        if (need & (1u << i)) {
          v[i] = __hip_atomic_load(src + (size_t)i * 512,
                                   __ATOMIC_RELAXED, __HIP_MEMORY_SCOPE_AGENT);
          if ((unsigned)(v[i] >> 32) == want) need &= ~(1u << i);
        }
    }
  };
  // stage bits into swizzled LDS: word nsw of row r at [r*64 + (nsw ^ ((r&15)<<2))]
  auto stage = [&](unsigned* bm, const unsigned long long (&v)[4]) {
#pragma unroll
    for (int i = 0; i < 4; ++i) {
      const int w = i * 512 + tid, r = w >> 6, nsw = w & 63;
      bm[r * 64 + (nsw ^ ((r & 15) << 2))] = (unsigned)v[i];
    }
  };
  // K-loop + split-K tree -> cI[2]; summation order verbatim r10 (absmax 0.0)
  auto gemm = [&](const unsigned* bm, float (&cI)[2]) {
    f32x4 acch[2][2], accl[2][2];
#pragma unroll
    for (int mt = 0; mt < 2; ++mt)
#pragma unroll
      for (int nt = 0; nt < 2; ++nt) { acch[mt][nt] = z4; accl[mt][nt] = z4; }
#pragma unroll
    for (int mt = 0; mt < 2; ++mt) {
      const int row = mt * 16 + l15;
      const int swz = l15 << 2;
      const u32x4 q0 = *(const u32x4*)&bm[row * 64 + ((kw * 8) ^ swz)];
      const u32x4 q1 = *(const u32x4*)&bm[row * 64 + (((kw * 8) | 4) ^ swz)];
#pragma unroll
      for (int kcl = 0; kcl < 8; ++kcl) {
        const unsigned word = (kcl < 4) ? q0[kcl] : q1[kcl - 4];
        const f16x8 a = expand8((word >> sh) & 0xFFu);
        acch[mt][0] = MFMA16(a, whf[0][kcl], acch[mt][0]);
        accl[mt][0] = MFMA16(a, wlf[0][kcl], accl[mt][0]);
        acch[mt][1] = MFMA16(a, whf[1][kcl], acch[mt][1]);
        accl[mt][1] = MFMA16(a, wlf[1][kcl], accl[mt][1]);
      }
    }
    f32x4 cb[2][2];
#pragma unroll
    for (int mt = 0; mt < 2; ++mt)
#pragma unroll
      for (int nt = 0; nt < 2; ++nt) cb[mt][nt] = acch[mt][nt] + accl[mt][nt] * inv4096;
    const int cbn = lane & 15, rq = (lane >> 4) << 2;
    if (kw >= 4) {
      const int p = kw - 4;
#pragma unroll
      for (int mt = 0; mt < 2; ++mt)
#pragma unroll
        for (int nt = 0; nt < 2; ++nt) {
          const int col = nt * 16 + cbn;
          const int r0 = (mt * 16 + rq) ^ ((col & 7) << 2);
          *(f32x4*)(red + (p * 32 + col) * 32 + r0) = cb[mt][nt];
        }
    }
    __syncthreads();
    if (kw < 4) {
#pragma unroll
      for (int mt = 0; mt < 2; ++mt)
#pragma unroll
        for (int nt = 0; nt < 2; ++nt) {
          const int col = nt * 16 + cbn;
          const int r0 = (mt * 16 + rq) ^ ((col & 7) << 2);
          float* p2 = red + (kw * 32 + col) * 32 + r0;
          f32x4 o = *(const f32x4*)p2;
          o += cb[mt][nt];
          *(f32x4*)p2 = o;
        }
    }
    __syncthreads();
#pragma unroll
    for (int j = 0; j < 2; ++j) {
      const int o = j * 512 + tid;
      const int row = o >> 5, col = o & 31;
      const int rs = row ^ ((col & 7) << 2);
      float s = 0.0f;
#pragma unroll
      for (int p = 0; p < 4; ++p) s += red[(p * 32 + col) * 32 + rs];
      cI[j] = s;
    }
  };
  // LIF + tagged spike stores (tag and bits in ONE u64: single-copy-atomic release-by-value)
  auto lif = [&](const float (&cI)[2], const float (&Ix)[2], float (&V)[2],
                 unsigned (&cnt)[2], int g, int nbuf, unsigned tag, bool dostore) {
#pragma unroll
    for (int j = 0; j < 2; ++j) {
      float I = cI[j] + Ix[j];
      float v = 0.9f * V[j] + I;
      bool sp = (v - 1.0f) >= 0.0f;
      V[j] = sp ? 0.0f : v;
      cnt[j] += sp ? 1u : 0u;
      if (dostore) {
        unsigned long long ba = __ballot(sp);
        const int rowf = g * 32 + j * 16 + kw * 2;  // lanes 0-31: rowf, 32-63: rowf+1
        const unsigned long long tg = ((unsigned long long)tag) << 32;
        if (lane == 0)
          __hip_atomic_store(bmv + (size_t)nbuf * 16384 + (size_t)rowf * 64 + ns,
                             tg | (unsigned)ba, __ATOMIC_RELAXED, __HIP_MEMORY_SCOPE_AGENT);
        else if (lane == 32)
          __hip_atomic_store(bmv + (size_t)nbuf * 16384 + (size_t)(rowf + 1) * 64 + ns,
                             tg | (unsigned)(ba >> 32), __ATOMIC_RELAXED, __HIP_MEMORY_SCOPE_AGENT);
      }
    }
  };

  // ---------- t = 0: Iext-only LIF; spikes tagged 1 -> buf 1; prefetch A ----------
  {
    const float cz[2] = {0.f, 0.f};
    lif(cz, IxA, VA, cA, gA, 1, 1u, true);
    lif(cz, IxB, VB, cB, gB, 1, 1u, true);
    spec_issue(gA, 1, vA);
  }

  for (int t = 1; t < T_STEPS; ++t) {
    const int cbuf = t & 1, nbuf = (t + 1) & 1;
    const bool last = (t == T_STEPS - 1);
    float cI[2];

    // ---- phase A ----
    check_retry(gA, cbuf, (unsigned)t, vA);
    stage(bmA, vA);
    __syncthreads();
    spec_issue(gB, cbuf, vB);            // in flight under gemm(A)
    gemm(bmA, cI);
    lif(cI, IxA, VA, cA, gA, nbuf, (unsigned)(t + 1), !last);

    // ---- phase B ----
    check_retry(gB, cbuf, (unsigned)t, vB);
    stage(bmB, vB);
    __syncthreads();
    if (!last) spec_issue(gA, nbuf, vA); // in flight under gemm(B)
    gemm(bmB, cI);
    lif(cI, IxB, VB, cB, gB, nbuf, (unsigned)(t + 1), !last);
  }

  // ---------- write firing rates ----------
#pragma unroll
  for (int j = 0; j < 2; ++j) {
    const int rA = gA * 32 + j * 16 + (tid >> 5);
    const int rB = gB * 32 + j * 16 + (tid >> 5);
    out[(size_t)rA * N_NEU + n0 + (tid & 31)] = (float)cA[j] * 0.015625f;
    out[(size_t)rB * N_NEU + n0 + (tid & 31)] = (float)cB[j] * 0.015625f;
  }
}

extern "C" void kernel_launch(void* const* d_in, const int* in_sizes, int n_in,
                              void* d_out, int out_size, void* d_ws, size_t ws_size,
                              hipStream_t stream) {
  (void)in_sizes; (void)n_in; (void)out_size; (void)ws_size;
  const float* ext  = (const float*)d_in[0];
  const float* Win  = (const float*)d_in[1];
  const float* bin  = (const float*)d_in[2];
  const float* adj  = (const float*)d_in[3];
  const float* mask = (const float*)d_in[4];
  unsigned char* ws = (unsigned char*)d_ws;

  _Float16* Wh   = (_Float16*)(ws);
  _Float16* Wl   = (_Float16*)(ws + (size_t)(8u << 20));
  float*    Iext = (float*)   (ws + (size_t)(16u << 20));
  unsigned long long* bmv = (unsigned long long*)(ws + (size_t)(18u << 20));
  float* out = (float*)d_out;

  hipLaunchKernelGGL(k_wsplit, dim3(2048), dim3(256), 0, stream, adj, mask, Wh, Wl, bmv);
  hipLaunchKernelGGL(k_iext,   dim3(128),  dim3(256), 0, stream, ext, Win, bin, Iext);
  hipLaunchKernelGGL(k_fused8, dim3(256),  dim3(512), 0, stream,
                     Wh, Wl, Iext, bmv, out);
}